// Round 7
// baseline (434.862 us; speedup 1.0000x reference)
//
#include <hip/hip_runtime.h>
#include <hip/hip_fp16.h>

#define BATCH 2
#define D_MODEL 1024
#define NH 16
#define DK 64
#define SEQ 2048

typedef _Float16 f16;
typedef __attribute__((ext_vector_type(8))) _Float16 f16x8;
typedef __attribute__((ext_vector_type(4))) _Float16 f16x4;
typedef __attribute__((ext_vector_type(4))) float f32x4;

// ---------------------------------------------------------------------------
// GEMM1: C = X(f32)[4096][1024] @ W(f32)[1024][1024]^T  (einsum bsd,od->bso)
// Output f16 into [b][h][s][dk] layout, optional fused RoPE.
// 128x128 tile, BK=32, 4 waves (2x2), each wave 64x64 via 4x4 16x16x32 MFMA.
// ---------------------------------------------------------------------------
__global__ __launch_bounds__(256) void gemm_qkv(const float* __restrict__ X,
                                                const float* __restrict__ W,
                                                f16* __restrict__ Out,
                                                int do_rope)
{
    constexpr int BK  = 32;
    constexpr int LDP = BK + 8;  // padded LDS stride (f16 elems); row = 80B
    __shared__ f16 As[128 * LDP];
    __shared__ f16 Bs[128 * LDP];

    const int tid  = threadIdx.x;
    const int lane = tid & 63;
    const int wave = tid >> 6;
    const int wm   = wave >> 1, wn = wave & 1;
    const int m0   = blockIdx.y * 128;
    const int n0   = blockIdx.x * 128;

    f32x4 acc[4][4] = {};

    const int srow = tid >> 3;        // 0..31
    const int scol = (tid & 7) * 4;   // 0,4,...,28

    for (int k0 = 0; k0 < 1024; k0 += BK) {
        __syncthreads();
        #pragma unroll
        for (int p = 0; p < 4; ++p) {
            int r = p * 32 + srow;
            float4 v = *(const float4*)(X + (size_t)(m0 + r) * 1024 + k0 + scol);
            f16x4 h; h[0]=(f16)v.x; h[1]=(f16)v.y; h[2]=(f16)v.z; h[3]=(f16)v.w;
            *(f16x4*)(As + r * LDP + scol) = h;
            float4 w = *(const float4*)(W + (size_t)(n0 + r) * 1024 + k0 + scol);
            f16x4 hw; hw[0]=(f16)w.x; hw[1]=(f16)w.y; hw[2]=(f16)w.z; hw[3]=(f16)w.w;
            *(f16x4*)(Bs + r * LDP + scol) = hw;
        }
        __syncthreads();

        const int kc = (lane >> 4) * 8;
        f16x8 a[4], b[4];
        #pragma unroll
        for (int i = 0; i < 4; ++i) {
            a[i] = *(const f16x8*)(As + (wm*64 + i*16 + (lane & 15)) * LDP + kc);
            b[i] = *(const f16x8*)(Bs + (wn*64 + i*16 + (lane & 15)) * LDP + kc);
        }
        #pragma unroll
        for (int i = 0; i < 4; ++i)
            #pragma unroll
            for (int j = 0; j < 4; ++j)
                acc[i][j] = __builtin_amdgcn_mfma_f32_16x16x32_f16(a[i], b[j], acc[i][j], 0, 0, 0);
    }

    // Epilogue: optional RoPE (pair = adjacent columns = adjacent lanes), then
    // scatter f16 to [b][h][s][dk].
    const int rbase = m0 + wm * 64 + ((lane >> 4) * 4);
    const int cbase = n0 + wn * 64 + (lane & 15);
    #pragma unroll
    for (int j = 0; j < 4; ++j) {
        const int o  = cbase + j * 16;
        const int hh = o >> 6;
        const int d  = o & 63;
        const float freq = do_rope ? powf(10000.f, -(float)(d >> 1) * (1.f / 32.f)) : 0.f;
        #pragma unroll
        for (int i = 0; i < 4; ++i) {
            #pragma unroll
            for (int r = 0; r < 4; ++r) {
                const int row = rbase + i * 16 + r;
                const int b   = row >> 11;
                const int s   = row & 2047;
                float v    = acc[i][j][r];
                float outv = v;
                if (do_rope) {
                    float partner = __shfl_xor(v, 1);
                    float ang = (float)s * freq;
                    float sn, cs;
                    sincosf(ang, &sn, &cs);
                    outv = (d & 1) ? (partner * sn + v * cs) : (v * cs - partner * sn);
                }
                Out[((size_t)(b * NH + hh) * SEQ + s) * DK + d] = (f16)outv;
            }
        }
    }
}

// ---------------------------------------------------------------------------
// Flash attention: per (q-block 64, head, batch). 4 waves, each 16 q-rows.
// Online softmax in LDS (m, l, scale arrays).
// ---------------------------------------------------------------------------
__global__ __launch_bounds__(256) void attn(const f16* __restrict__ Q,
                                            const f16* __restrict__ K,
                                            const f16* __restrict__ V,
                                            f16* __restrict__ O)
{
    constexpr int SP = 72;  // padded stride
    __shared__ f16   Kt[64 * SP];
    __shared__ f16   VtT[64 * SP];   // transposed: [d][k]
    __shared__ float St[64 * SP];
    __shared__ f16   Pt[64 * SP];
    __shared__ float m_s[64], l_s[64], sc_s[64];

    const int tid  = threadIdx.x;
    const int lane = tid & 63;
    const int w    = tid >> 6;
    const int qb = blockIdx.x, hh = blockIdx.y, b = blockIdx.z;
    const int q0 = qb * 64;
    const size_t base = (size_t)(b * NH + hh) * SEQ * DK;

    // Q fragments (A operand): row = q0 + w*16 + (lane&15), k chunks of 8
    f16x8 qf[2];
    {
        const int qrow = q0 + w * 16 + (lane & 15);
        const f16* qp = Q + base + (size_t)qrow * DK + ((lane >> 4) * 8);
        qf[0] = *(const f16x8*)(qp);
        qf[1] = *(const f16x8*)(qp + 32);
    }
    f32x4 acc[4] = {};
    if (tid < 64) { m_s[tid] = -INFINITY; l_s[tid] = 0.f; }

    for (int kb = 0; kb <= qb; ++kb) {
        __syncthreads();
        // stage K tile [64][64] row-major, V tile transposed [d][k]
        {
            int c = tid;
            #pragma unroll
            for (int it = 0; it < 2; ++it, c += 256) {
                const int kk = c >> 3;
                const int dc = (c & 7) * 8;
                f16x8 kv = *(const f16x8*)(K + base + (size_t)(kb * 64 + kk) * DK + dc);
                *(f16x8*)(Kt + kk * SP + dc) = kv;
                f16x8 vv = *(const f16x8*)(V + base + (size_t)(kb * 64 + kk) * DK + dc);
                #pragma unroll
                for (int e = 0; e < 8; ++e) VtT[(dc + e) * SP + kk] = vv[e];
            }
        }
        __syncthreads();

        // QK^T -> St (scaled, causal-masked)
        #pragma unroll
        for (int nt = 0; nt < 4; ++nt) {
            f32x4 sc = {};
            const f16* kp = Kt + (nt * 16 + (lane & 15)) * SP + ((lane >> 4) * 8);
            sc = __builtin_amdgcn_mfma_f32_16x16x32_f16(qf[0], *(const f16x8*)kp,        sc, 0, 0, 0);
            sc = __builtin_amdgcn_mfma_f32_16x16x32_f16(qf[1], *(const f16x8*)(kp + 32), sc, 0, 0, 0);
            const int kl = nt * 16 + (lane & 15);
            #pragma unroll
            for (int r = 0; r < 4; ++r) {
                const int ql = w * 16 + ((lane >> 4) * 4) + r;
                float sv = sc[r] * 0.125f;
                if (kb == qb && kl > ql) sv = -INFINITY;
                St[ql * SP + kl] = sv;
            }
        }
        __syncthreads();

        // online softmax: 4 threads per row, 16 cols each
        {
            const int row = tid >> 2, part = tid & 3;
            float pv[16];
            float mx = -INFINITY;
            #pragma unroll
            for (int i = 0; i < 16; ++i) {
                pv[i] = St[row * SP + part * 16 + i];
                mx = fmaxf(mx, pv[i]);
            }
            mx = fmaxf(mx, __shfl_xor(mx, 1));
            mx = fmaxf(mx, __shfl_xor(mx, 2));
            const float m_old = m_s[row];
            const float m_new = fmaxf(m_old, mx);
            float sum = 0.f;
            #pragma unroll
            for (int i = 0; i < 16; ++i) {
                float p = __expf(pv[i] - m_new);
                sum += p;
                Pt[row * SP + part * 16 + i] = (f16)p;
            }
            sum += __shfl_xor(sum, 1);
            sum += __shfl_xor(sum, 2);
            if (part == 0) {
                const float scale = __expf(m_old - m_new);
                l_s[row] = l_s[row] * scale + sum;
                m_s[row] = m_new;
                sc_s[row] = scale;
            }
        }
        __syncthreads();

        // rescale acc + PV
        {
            #pragma unroll
            for (int r = 0; r < 4; ++r) {
                const float s = sc_s[w * 16 + ((lane >> 4) * 4) + r];
                #pragma unroll
                for (int nt = 0; nt < 4; ++nt) acc[nt][r] *= s;
            }
            f16x8 pa[2];
            const f16* pp = Pt + (w * 16 + (lane & 15)) * SP + ((lane >> 4) * 8);
            pa[0] = *(const f16x8*)pp;
            pa[1] = *(const f16x8*)(pp + 32);
            #pragma unroll
            for (int nt = 0; nt < 4; ++nt) {
                const f16* vp = VtT + (nt * 16 + (lane & 15)) * SP + ((lane >> 4) * 8);
                acc[nt] = __builtin_amdgcn_mfma_f32_16x16x32_f16(pa[0], *(const f16x8*)vp,        acc[nt], 0, 0, 0);
                acc[nt] = __builtin_amdgcn_mfma_f32_16x16x32_f16(pa[1], *(const f16x8*)(vp + 32), acc[nt], 0, 0, 0);
            }
        }
    }

    // epilogue: O[b][s][hh*64+d] = acc / l
    #pragma unroll
    for (int r = 0; r < 4; ++r) {
        const int ql  = w * 16 + ((lane >> 4) * 4) + r;
        const float inv = 1.f / l_s[ql];
        const int s = q0 + ql;
        #pragma unroll
        for (int nt = 0; nt < 4; ++nt) {
            const int d = nt * 16 + (lane & 15);
            O[((size_t)(b * SEQ + s)) * D_MODEL + hh * 64 + d] = (f16)(acc[nt][r] * inv);
        }
    }
}

// ---------------------------------------------------------------------------
// GEMM2: out(f32) = AO(f16)[4096][1024] @ Wo(f32)[1024][1024]^T
// ---------------------------------------------------------------------------
__global__ __launch_bounds__(256) void gemm_out(const f16* __restrict__ A,
                                                const float* __restrict__ W,
                                                float* __restrict__ Cout)
{
    constexpr int BK  = 32;
    constexpr int LDP = BK + 8;
    __shared__ f16 As[128 * LDP];
    __shared__ f16 Bs[128 * LDP];

    const int tid  = threadIdx.x;
    const int lane = tid & 63;
    const int wave = tid >> 6;
    const int wm   = wave >> 1, wn = wave & 1;
    const int m0   = blockIdx.y * 128;
    const int n0   = blockIdx.x * 128;

    f32x4 acc[4][4] = {};

    const int srow = tid >> 3;
    const int scol = (tid & 7) * 4;
    const int arow = tid >> 2;
    const int acol = (tid & 3) * 8;

    for (int k0 = 0; k0 < 1024; k0 += BK) {
        __syncthreads();
        #pragma unroll
        for (int p = 0; p < 2; ++p) {
            int r = p * 64 + arow;
            f16x8 v = *(const f16x8*)(A + (size_t)(m0 + r) * 1024 + k0 + acol);
            *(f16x8*)(As + r * LDP + acol) = v;
        }
        #pragma unroll
        for (int p = 0; p < 4; ++p) {
            int r = p * 32 + srow;
            float4 w = *(const float4*)(W + (size_t)(n0 + r) * 1024 + k0 + scol);
            f16x4 hw; hw[0]=(f16)w.x; hw[1]=(f16)w.y; hw[2]=(f16)w.z; hw[3]=(f16)w.w;
            *(f16x4*)(Bs + r * LDP + scol) = hw;
        }
        __syncthreads();

        const int kc = (lane >> 4) * 8;
        f16x8 a[4], b[4];
        #pragma unroll
        for (int i = 0; i < 4; ++i) {
            a[i] = *(const f16x8*)(As + (wm*64 + i*16 + (lane & 15)) * LDP + kc);
            b[i] = *(const f16x8*)(Bs + (wn*64 + i*16 + (lane & 15)) * LDP + kc);
        }
        #pragma unroll
        for (int i = 0; i < 4; ++i)
            #pragma unroll
            for (int j = 0; j < 4; ++j)
                acc[i][j] = __builtin_amdgcn_mfma_f32_16x16x32_f16(a[i], b[j], acc[i][j], 0, 0, 0);
    }

    #pragma unroll
    for (int i = 0; i < 4; ++i)
        #pragma unroll
        for (int j = 0; j < 4; ++j)
            #pragma unroll
            for (int r = 0; r < 4; ++r) {
                const int row = m0 + wm*64 + i*16 + ((lane >> 4) * 4) + r;
                const int col = n0 + wn*64 + j*16 + (lane & 15);
                Cout[(size_t)row * 1024 + col] = acc[i][j][r];
            }
}

// ---------------------------------------------------------------------------
extern "C" void kernel_launch(void* const* d_in, const int* in_sizes, int n_in,
                              void* d_out, int out_size, void* d_ws, size_t ws_size,
                              hipStream_t stream)
{
    const float* x  = (const float*)d_in[0];
    const float* Wq = (const float*)d_in[1];
    const float* Wk = (const float*)d_in[2];
    const float* Wv = (const float*)d_in[3];
    const float* Wo = (const float*)d_in[4];
    float* out = (float*)d_out;

    const size_t NE = (size_t)BATCH * SEQ * D_MODEL;  // 4194304
    f16* Qr = (f16*)d_ws;
    f16* Kr = Qr + NE;
    f16* Vr = Kr + NE;
    f16* AO = Vr + NE;

    dim3 blk(256);
    dim3 g1(8, 32);
    gemm_qkv<<<g1, blk, 0, stream>>>(x, Wq, Qr, 1);
    gemm_qkv<<<g1, blk, 0, stream>>>(x, Wk, Kr, 1);
    gemm_qkv<<<g1, blk, 0, stream>>>(x, Wv, Vr, 0);

    dim3 ga(SEQ / 64, NH, BATCH);
    attn<<<ga, blk, 0, stream>>>(Qr, Kr, Vr, AO);

    gemm_out<<<g1, blk, 0, stream>>>(AO, Wo, out);
}

// Round 9
// 369.999 us; speedup vs baseline: 1.1753x; 1.1753x over previous
//
#include <hip/hip_runtime.h>
#include <hip/hip_fp16.h>

#define BATCH 2
#define D_MODEL 1024
#define NH 16
#define DK 64
#define SEQ 2048

typedef _Float16 f16;
typedef __attribute__((ext_vector_type(8))) _Float16 f16x8;
typedef __attribute__((ext_vector_type(4))) _Float16 f16x4;
typedef __attribute__((ext_vector_type(4))) float f32x4;

// ---------------------------------------------------------------------------
// Fused QKV GEMM: C = X(f32)[4096][1024] @ [Wq;Wk;Wv]^T  -> N = 3072
// Output f16 into per-segment [b][h][s][dk] buffers, RoPE fused for Q,K.
// 128x128 tile, BK=32, 4 waves (2x2). grid (24, 32) = 768 blocks = 3/CU.
// ---------------------------------------------------------------------------
__global__ __launch_bounds__(256) void gemm_qkv(const float* __restrict__ X,
                                                const float* __restrict__ Wq,
                                                const float* __restrict__ Wk,
                                                const float* __restrict__ Wv,
                                                f16* __restrict__ WS)
{
    constexpr int BK  = 32;
    constexpr int LDP = BK + 8;  // 80B rows (16B-aligned)
    __shared__ f16 As[128 * LDP];
    __shared__ f16 Bs[128 * LDP];

    const int tid  = threadIdx.x;
    const int lane = tid & 63;
    const int wave = tid >> 6;
    const int wm   = wave >> 1, wn = wave & 1;
    const int m0   = blockIdx.y * 128;
    const int n0   = blockIdx.x * 128;     // global col in 0..3071
    const int seg  = n0 >> 10;             // 0=Q 1=K 2=V (whole block in one seg)
    const int nloc = n0 & 1023;
    const float* __restrict__ W = (seg == 0) ? Wq : (seg == 1 ? Wk : Wv);
    const int do_rope = (seg < 2);
    f16* __restrict__ Out = WS + (size_t)seg * BATCH * SEQ * D_MODEL;

    f32x4 acc[4][4] = {};

    const int srow = tid >> 3;        // 0..31
    const int scol = (tid & 7) * 4;   // 0,4,...,28

    for (int k0 = 0; k0 < 1024; k0 += BK) {
        __syncthreads();
        #pragma unroll
        for (int p = 0; p < 4; ++p) {
            int r = p * 32 + srow;
            float4 v = *(const float4*)(X + (size_t)(m0 + r) * 1024 + k0 + scol);
            f16x4 h; h[0]=(f16)v.x; h[1]=(f16)v.y; h[2]=(f16)v.z; h[3]=(f16)v.w;
            *(f16x4*)(As + r * LDP + scol) = h;
            float4 w = *(const float4*)(W + (size_t)(nloc + r) * 1024 + k0 + scol);
            f16x4 hw; hw[0]=(f16)w.x; hw[1]=(f16)w.y; hw[2]=(f16)w.z; hw[3]=(f16)w.w;
            *(f16x4*)(Bs + r * LDP + scol) = hw;
        }
        __syncthreads();

        const int kc = (lane >> 4) * 8;
        f16x8 a[4], b[4];
        #pragma unroll
        for (int i = 0; i < 4; ++i) {
            a[i] = *(const f16x8*)(As + (wm*64 + i*16 + (lane & 15)) * LDP + kc);
            b[i] = *(const f16x8*)(Bs + (wn*64 + i*16 + (lane & 15)) * LDP + kc);
        }
        #pragma unroll
        for (int i = 0; i < 4; ++i)
            #pragma unroll
            for (int j = 0; j < 4; ++j)
                acc[i][j] = __builtin_amdgcn_mfma_f32_16x16x32_f16(a[i], b[j], acc[i][j], 0, 0, 0);
    }

    // Epilogue: RoPE via adjacent-lane pairing (col parity == lane parity)
    const int rbase = m0 + wm * 64 + ((lane >> 4) * 4);
    const int cbase = nloc + wn * 64 + (lane & 15);
    #pragma unroll
    for (int j = 0; j < 4; ++j) {
        const int o  = cbase + j * 16;        // col within segment
        const int hh = o >> 6;
        const int d  = o & 63;
        const float freq = do_rope ? powf(10000.f, -(float)(d >> 1) * (1.f / 32.f)) : 0.f;
        #pragma unroll
        for (int i = 0; i < 4; ++i) {
            #pragma unroll
            for (int r = 0; r < 4; ++r) {
                const int row = rbase + i * 16 + r;
                const int b   = row >> 11;
                const int s   = row & 2047;
                float v    = acc[i][j][r];
                float outv = v;
                float partner = __shfl_xor(v, 1);
                if (do_rope) {
                    float ang = (float)s * freq;
                    float sn, cs;
                    sincosf(ang, &sn, &cs);
                    outv = (d & 1) ? (partner * sn + v * cs) : (v * cs - partner * sn);
                }
                Out[((size_t)(b * NH + hh) * SEQ + s) * DK + d] = (f16)outv;
            }
        }
    }
}

// ---------------------------------------------------------------------------
// Flash attention, in-register online softmax.
// Per block: 64 q-rows, 4 waves (16 rows each), KV tiles of 64.
// K row-major [k][d]; V transposed [d][k] with XOR swizzle on the k index
// (col ^= ((d>>3)&3)<<3) so the transposed scalar stores spread banks.
// Softmax: C-layout row (q) lives in 16 contiguous lanes -> shfl_xor reduce.
// P goes through LDS (Pt) only for the C->A fragment relayout (same wave,
// no barrier needed).  2 barriers per kv-tile (around K/V staging).
// ---------------------------------------------------------------------------
__global__ __launch_bounds__(256) void attn(const f16* __restrict__ Q,
                                            const f16* __restrict__ K,
                                            const f16* __restrict__ V,
                                            f16* __restrict__ O)
{
    constexpr int SP = 72;              // f16 stride = 144B (16B aligned)
    __shared__ f16 Kt[64 * SP];
    __shared__ f16 Vt[64 * SP];         // [d][k^swz]
    __shared__ f16 Pt[64 * SP];

    const int tid  = threadIdx.x;
    const int lane = tid & 63;
    const int w    = tid >> 6;
    const int g    = lane >> 4;         // 0..3
    const int l15  = lane & 15;
    const int qb = blockIdx.x, hh = blockIdx.y, b = blockIdx.z;
    const int q0 = qb * 64;
    const size_t base = (size_t)(b * NH + hh) * SEQ * DK;

    // Q fragments (A operand): row = q0 + w*16 + l15, k chunks of 8
    f16x8 qf[2];
    {
        const f16* qp = Q + base + (size_t)(q0 + w * 16 + l15) * DK + g * 8;
        qf[0] = *(const f16x8*)(qp);
        qf[1] = *(const f16x8*)(qp + 32);
    }
    f32x4 acc[4] = {};
    float m_reg[4] = {-INFINITY, -INFINITY, -INFINITY, -INFINITY};
    float l_reg[4] = {0.f, 0.f, 0.f, 0.f};

    for (int kb = 0; kb <= qb; ++kb) {
        __syncthreads();
        // stage K row-major + V transposed-swizzled
        {
            #pragma unroll
            for (int it = 0; it < 2; ++it) {
                const int c  = tid + it * 256;
                const int kk = c >> 3;          // 0..63
                const int dc = (c & 7) * 8;     // 0..56
                f16x8 kv = *(const f16x8*)(K + base + (size_t)(kb * 64 + kk) * DK + dc);
                *(f16x8*)(Kt + kk * SP + dc) = kv;
                f16x8 vv = *(const f16x8*)(V + base + (size_t)(kb * 64 + kk) * DK + dc);
                const int swz = ((dc >> 3) & 3) << 3;   // (d>>3)&3 == (dc>>3)&3 for e<8
                #pragma unroll
                for (int e = 0; e < 8; ++e)
                    Vt[(dc + e) * SP + (kk ^ swz)] = vv[e];
            }
        }
        __syncthreads();

        // QK^T (C layout: col k = l15+16*nt, row q = w*16 + g*4 + r)
        f32x4 s[4];
        #pragma unroll
        for (int nt = 0; nt < 4; ++nt) {
            f32x4 z = {};
            const f16* kp = Kt + (nt * 16 + l15) * SP + g * 8;
            z = __builtin_amdgcn_mfma_f32_16x16x32_f16(qf[0], *(const f16x8*)kp,        z, 0, 0, 0);
            z = __builtin_amdgcn_mfma_f32_16x16x32_f16(qf[1], *(const f16x8*)(kp + 32), z, 0, 0, 0);
            s[nt] = z;
        }

        // in-register online softmax (per r: row q = w*16+g*4+r)
        #pragma unroll
        for (int r = 0; r < 4; ++r) {
            const int qloc = w * 16 + g * 4 + r;
            float va[4];
            #pragma unroll
            for (int nt = 0; nt < 4; ++nt) {
                float sv = s[nt][r] * 0.125f;
                if (kb == qb && (nt * 16 + l15) > qloc) sv = -INFINITY;
                va[nt] = sv;
            }
            float mx = fmaxf(fmaxf(va[0], va[1]), fmaxf(va[2], va[3]));
            mx = fmaxf(mx, __shfl_xor(mx, 1));
            mx = fmaxf(mx, __shfl_xor(mx, 2));
            mx = fmaxf(mx, __shfl_xor(mx, 4));
            mx = fmaxf(mx, __shfl_xor(mx, 8));
            const float mnew = fmaxf(m_reg[r], mx);
            const float scl  = __expf(m_reg[r] - mnew);
            m_reg[r] = mnew;
            float ps = 0.f;
            #pragma unroll
            for (int nt = 0; nt < 4; ++nt) {
                float p = __expf(va[nt] - mnew);
                ps += p;
                Pt[qloc * SP + nt * 16 + l15] = (f16)p;
            }
            ps += __shfl_xor(ps, 1);
            ps += __shfl_xor(ps, 2);
            ps += __shfl_xor(ps, 4);
            ps += __shfl_xor(ps, 8);
            l_reg[r] = l_reg[r] * scl + ps;
            #pragma unroll
            for (int nt = 0; nt < 4; ++nt) acc[nt][r] *= scl;
        }

        // PV: P A-fragment from Pt (same-wave rows, no barrier),
        //     V^T B-fragment from swizzled Vt.
        {
            f16x8 pa[2];
            const f16* pp = Pt + (w * 16 + l15) * SP + g * 8;
            pa[0] = *(const f16x8*)pp;
            pa[1] = *(const f16x8*)(pp + 32);
            #pragma unroll
            for (int nt = 0; nt < 4; ++nt) {
                const int d = nt * 16 + l15;
                const int m = ((d >> 3) & 3);
                const int c0 = ((g ^ m) << 3);          // swizzled chunk for ks=0
                const f16* vp = Vt + d * SP;
                f16x8 vb0 = *(const f16x8*)(vp + c0);
                f16x8 vb1 = *(const f16x8*)(vp + c0 + 32);
                acc[nt] = __builtin_amdgcn_mfma_f32_16x16x32_f16(pa[0], vb0, acc[nt], 0, 0, 0);
                acc[nt] = __builtin_amdgcn_mfma_f32_16x16x32_f16(pa[1], vb1, acc[nt], 0, 0, 0);
            }
        }
    }

    // epilogue: O[b][s][hh*64+d] = acc / l   (l replicated across 16 lanes)
    #pragma unroll
    for (int r = 0; r < 4; ++r) {
        const float inv = 1.f / l_reg[r];
        const int s = q0 + w * 16 + g * 4 + r;
        #pragma unroll
        for (int nt = 0; nt < 4; ++nt) {
            const int d = nt * 16 + l15;
            O[((size_t)(b * SEQ + s)) * D_MODEL + hh * 64 + d] = (f16)(acc[nt][r] * inv);
        }
    }
}

// ---------------------------------------------------------------------------
// GEMM2: out(f32) = AO(f16)[4096][1024] @ Wo(f32)[1024][1024]^T
// BM=64, BN=128 -> grid (8,64) = 512 blocks = 2/CU.  4 waves 2x2, wave 32x64.
// ---------------------------------------------------------------------------
__global__ __launch_bounds__(256) void gemm_out(const f16* __restrict__ A,
                                                const float* __restrict__ W,
                                                float* __restrict__ Cout)
{
    constexpr int BK  = 32;
    constexpr int LDP = BK + 8;
    __shared__ f16 As[64 * LDP];
    __shared__ f16 Bs[128 * LDP];

    const int tid  = threadIdx.x;
    const int lane = tid & 63;
    const int wave = tid >> 6;
    const int wm   = wave >> 1, wn = wave & 1;     // wave tile 32x64
    const int m0   = blockIdx.y * 64;
    const int n0   = blockIdx.x * 128;

    f32x4 acc[2][4] = {};

    const int srow = tid >> 3;        // 0..31 (B stage)
    const int scol = (tid & 7) * 4;
    const int arow = tid >> 2;        // 0..63 (A stage)
    const int acol = (tid & 3) * 8;

    for (int k0 = 0; k0 < 1024; k0 += BK) {
        __syncthreads();
        {
            f16x8 v = *(const f16x8*)(A + (size_t)(m0 + arow) * 1024 + k0 + acol);
            *(f16x8*)(As + arow * LDP + acol) = v;
        }
        #pragma unroll
        for (int p = 0; p < 4; ++p) {
            int r = p * 32 + srow;
            float4 w = *(const float4*)(W + (size_t)(n0 + r) * 1024 + k0 + scol);
            f16x4 hw; hw[0]=(f16)w.x; hw[1]=(f16)w.y; hw[2]=(f16)w.z; hw[3]=(f16)w.w;
            *(f16x4*)(Bs + r * LDP + scol) = hw;
        }
        __syncthreads();

        const int kc = (lane >> 4) * 8;
        f16x8 a[2], b[4];
        #pragma unroll
        for (int i = 0; i < 2; ++i)
            a[i] = *(const f16x8*)(As + (wm*32 + i*16 + (lane & 15)) * LDP + kc);
        #pragma unroll
        for (int j = 0; j < 4; ++j)
            b[j] = *(const f16x8*)(Bs + (wn*64 + j*16 + (lane & 15)) * LDP + kc);
        #pragma unroll
        for (int i = 0; i < 2; ++i)
            #pragma unroll
            for (int j = 0; j < 4; ++j)
                acc[i][j] = __builtin_amdgcn_mfma_f32_16x16x32_f16(a[i], b[j], acc[i][j], 0, 0, 0);
    }

    #pragma unroll
    for (int i = 0; i < 2; ++i)
        #pragma unroll
        for (int j = 0; j < 4; ++j)
            #pragma unroll
            for (int r = 0; r < 4; ++r) {
                const int row = m0 + wm*32 + i*16 + ((lane >> 4) * 4) + r;
                const int col = n0 + wn*64 + j*16 + (lane & 15);
                Cout[(size_t)row * 1024 + col] = acc[i][j][r];
            }
}

// ---------------------------------------------------------------------------
extern "C" void kernel_launch(void* const* d_in, const int* in_sizes, int n_in,
                              void* d_out, int out_size, void* d_ws, size_t ws_size,
                              hipStream_t stream)
{
    const float* x  = (const float*)d_in[0];
    const float* Wq = (const float*)d_in[1];
    const float* Wk = (const float*)d_in[2];
    const float* Wv = (const float*)d_in[3];
    const float* Wo = (const float*)d_in[4];
    float* out = (float*)d_out;

    const size_t NE = (size_t)BATCH * SEQ * D_MODEL;  // 4194304
    f16* Qr = (f16*)d_ws;
    f16* Kr = Qr + NE;
    f16* Vr = Kr + NE;
    f16* AO = Vr + NE;

    dim3 blk(256);
    gemm_qkv<<<dim3(24, 32), blk, 0, stream>>>(x, Wq, Wk, Wv, Qr);

    attn<<<dim3(SEQ / 64, NH, BATCH), blk, 0, stream>>>(Qr, Kr, Vr, AO);

    gemm_out<<<dim3(8, 64), blk, 0, stream>>>(AO, Wo, out);
}